// Round 2
// baseline (29640.277 us; speedup 1.0000x reference)
//
#include <hip/hip_runtime.h>
#include <math.h>

// resRNN forward: N=256, L=1024, inp=521 (=8 x + 1 storage + 512 hx), HID=512, OUT=1.
// Round 2 (fixed): W1 is step-invariant -> make it resident. Rows [0,160) live in
// VGPRs (thread j caches its column), rows [160,232) in LDS (144 KB), rows [232,521)
// streamed from L2 with depth-4 rolling prefetch. Streamed bytes/step/CU drop
// 1.07 MB -> 592 KB (the measured bottleneck was the L2->CU port).
// inp staging is interleaved {b0[k],b1[k]} so one b128 broadcast feeds 2 rows x 2 batches.
// NOTE: macro param must NOT be named `w` (collides with float4 member .w).

constexpr int kN   = 256;
constexpr int kL   = 1024;
constexpr int kHin = 8;
constexpr int kHid = 512;
constexpr int kInp = kHin + 1 + kHid;        // 521
constexpr int kBlk = 512;                    // threads per block
constexpr int kBpb = 2;                      // batch elements per block

constexpr int RREG = 160;                    // W1 rows resident in VGPRs
constexpr int RLDS = 72;                     // W1 rows resident in LDS (144 KB)
constexpr int RRES = RREG + RLDS;            // 232 resident rows
constexpr int NCH  = (kInp - 1 - RRES) / 8;  // 36 streamed chunks of 8 rows (+1 tail row)
static_assert(RRES + 8 * NCH + 1 == kInp, "row partition must cover 521 rows");

// Consume 8 streamed rows starting at row kb using weight buffer WB[0..7].
#define CONSUME8(kb, WB)                                                         \
  {                                                                              \
    const float4 va = *reinterpret_cast<const float4*>(&inps[2 * (kb)]);         \
    const float4 vb = *reinterpret_cast<const float4*>(&inps[2 * (kb) + 4]);     \
    const float4 vc = *reinterpret_cast<const float4*>(&inps[2 * (kb) + 8]);     \
    const float4 vd = *reinterpret_cast<const float4*>(&inps[2 * (kb) + 12]);    \
    a0 = fmaf(va.x, (WB)[0], a0); a1 = fmaf(va.y, (WB)[0], a1);                  \
    c0 = fmaf(va.z, (WB)[1], c0); c1 = fmaf(va.w, (WB)[1], c1);                  \
    a0 = fmaf(vb.x, (WB)[2], a0); a1 = fmaf(vb.y, (WB)[2], a1);                  \
    c0 = fmaf(vb.z, (WB)[3], c0); c1 = fmaf(vb.w, (WB)[3], c1);                  \
    a0 = fmaf(vc.x, (WB)[4], a0); a1 = fmaf(vc.y, (WB)[4], a1);                  \
    c0 = fmaf(vc.z, (WB)[5], c0); c1 = fmaf(vc.w, (WB)[5], c1);                  \
    a0 = fmaf(vd.x, (WB)[6], a0); a1 = fmaf(vd.y, (WB)[6], a1);                  \
    c0 = fmaf(vd.z, (WB)[7], c0); c1 = fmaf(vd.w, (WB)[7], c1);                  \
  }

// Load streamed chunk ch (8 rows) into buf[0..7]; coalesced column reads.
#define LOAD8(buf, ch)                                                           \
  {                                                                              \
    const float* _p = wstr + (size_t)(8 * (ch)) * kHid;                          \
    (buf)[0] = _p[0 * kHid]; (buf)[1] = _p[1 * kHid];                            \
    (buf)[2] = _p[2 * kHid]; (buf)[3] = _p[3 * kHid];                            \
    (buf)[4] = _p[4 * kHid]; (buf)[5] = _p[5 * kHid];                            \
    (buf)[6] = _p[6 * kHid]; (buf)[7] = _p[7 * kHid];                            \
  }

__global__ __launch_bounds__(kBlk, 2)
void resrnn_fwd(const float* __restrict__ x, const float* __restrict__ W1,
                const float* __restrict__ b1, const float* __restrict__ W2,
                const float* __restrict__ b2, float* __restrict__ out) {
  // inps: interleaved pairs {batch0[k], batch1[k]} for k in [0,521)
  __shared__ __align__(16) float inps[2 * kInp + 2];
  __shared__ float wlds[RLDS][kHid];   // W1 rows [RREG, RRES), 144 KB
  __shared__ float red[8][2];

  const int j  = threadIdx.x;          // hidden column 0..511
  const int n0 = blockIdx.x * kBpb;
  const int n1 = n0 + 1;

  const float b2v = b2[0];
  const float w2j = W2[j];
  const float b1j = b1[j];

  float* const outp = out;                        // (N,L,1) flat
  float* const stor = out + (size_t)kN * kL;      // implied_storage

  const float* x0 = x + (size_t)n0 * kL * kHin;
  const float* x1 = x + (size_t)n1 * kL * kHin;

  const float* const wj   = W1 + j;               // column j, stride kHid
  const float* const wstr = wj + (size_t)RRES * kHid;

  // ---- one-time W1 cache fill ----
  float wreg[RREG];
  #pragma unroll
  for (int r = 0; r < RREG; ++r) wreg[r] = wj[(size_t)r * kHid];
  for (int r = 0; r < RLDS; ++r) wlds[r][j] = wj[(size_t)(RREG + r) * kHid];

  // ---- init: hx = 0, s_0 = x_0[0] ----
  {
    float2 z; z.x = 0.f; z.y = 0.f;
    *reinterpret_cast<float2*>(&inps[2 * (kHin + 1 + j)]) = z;
  }
  float s0 = x0[0];
  float s1 = x1[0];
  if (j < kHin) { inps[2 * j] = x0[j]; inps[2 * j + 1] = x1[j]; }
  if (j == 8)   { inps[2 * kHin] = s0; inps[2 * kHin + 1] = s1; }
  if (j == 0) {
    stor[(size_t)n0 * kL] = s0;
    stor[(size_t)n1 * kL] = s1;
  }
  __syncthreads();

  for (int t = 0; t < kL; ++t) {
    float a0 = b1j, a1 = b1j;   // fma chain A (even rows)
    float c0 = 0.f, c1 = 0.f;   // fma chain B (odd rows)

    // issue first 4 streamed chunks + tail row early (hide L2 latency under
    // the resident-row FMA phases below)
    float bA[8], bB[8], bC[8], bD[8];
    LOAD8(bA, 0) LOAD8(bB, 1) LOAD8(bC, 2) LOAD8(bD, 3)
    const float wtail = wj[(size_t)(kInp - 1) * kHid];

    // ---- rows [0, RREG): weights in VGPRs, inputs via LDS broadcast ----
    #pragma unroll
    for (int k = 0; k < RREG; k += 2) {
      const float4 v = *reinterpret_cast<const float4*>(&inps[2 * k]);
      a0 = fmaf(v.x, wreg[k], a0);     a1 = fmaf(v.y, wreg[k], a1);
      c0 = fmaf(v.z, wreg[k + 1], c0); c1 = fmaf(v.w, wreg[k + 1], c1);
    }

    // ---- rows [RREG, RRES): weights in LDS (lane-consecutive, conflict-free) ----
    #pragma unroll 4
    for (int k = 0; k < RLDS; k += 2) {
      const float4 v = *reinterpret_cast<const float4*>(&inps[2 * (RREG + k)]);
      const float wa = wlds[k][j];
      const float wb = wlds[k + 1][j];
      a0 = fmaf(v.x, wa, a0); a1 = fmaf(v.y, wa, a1);
      c0 = fmaf(v.z, wb, c0); c1 = fmaf(v.w, wb, c1);
    }

    // ---- rows [RRES, 520): streamed from L2, depth-4 rolling prefetch ----
    #pragma unroll 1
    for (int cc = 0; cc < NCH / 4; ++cc) {
      const int ch = 4 * cc;
      CONSUME8(RRES + 8 * (ch + 0), bA)
      if (cc < NCH / 4 - 1) { LOAD8(bA, ch + 4) }
      CONSUME8(RRES + 8 * (ch + 1), bB)
      if (cc < NCH / 4 - 1) { LOAD8(bB, ch + 5) }
      CONSUME8(RRES + 8 * (ch + 2), bC)
      if (cc < NCH / 4 - 1) { LOAD8(bC, ch + 6) }
      CONSUME8(RRES + 8 * (ch + 3), bD)
      if (cc < NCH / 4 - 1) { LOAD8(bD, ch + 7) }
    }
    {  // tail row k = 520
      const float2 v = *reinterpret_cast<const float2*>(&inps[2 * (kInp - 1)]);
      a0 = fmaf(v.x, wtail, a0);
      a1 = fmaf(v.y, wtail, a1);
    }

    const float h0 = tanhf(a0 + c0);
    const float h1 = tanhf(a1 + c1);

    // ---- out = hx_new . W2 + b2 : wave shuffle reduce, then LDS combine ----
    float p0 = h0 * w2j;
    float p1 = h1 * w2j;
    #pragma unroll
    for (int off = 32; off > 0; off >>= 1) {
      p0 += __shfl_down(p0, off, 64);
      p1 += __shfl_down(p1, off, 64);
    }
    const int lane = j & 63, wid = j >> 6;
    if (lane == 0) { red[wid][0] = p0; red[wid][1] = p1; }
    __syncthreads();  // barrier A: all inps reads done; red[] populated

    float d0 = 0.f, d1 = 0.f;
    #pragma unroll
    for (int q = 0; q < 8; ++q) { d0 += red[q][0]; d1 += red[q][1]; }
    const float o0 = d0 + b2v;  // identical in every thread
    const float o1 = d1 + b2v;
    if (j == 0) {
      outp[(size_t)n0 * kL + t] = o0;
      outp[(size_t)n1 * kL + t] = o1;
    }

    // ---- stage step t+1: hx, x, s = s + x_{t+1}[0] - out_t ----
    {
      float2 hv; hv.x = h0; hv.y = h1;
      *reinterpret_cast<float2*>(&inps[2 * (kHin + 1 + j)]) = hv;
    }
    if (t + 1 < kL) {
      const float* xr0 = x0 + (size_t)(t + 1) * kHin;
      const float* xr1 = x1 + (size_t)(t + 1) * kHin;
      s0 += xr0[0] - o0;  // replicated identically across threads
      s1 += xr1[0] - o1;
      if (j < kHin) { inps[2 * j] = xr0[j]; inps[2 * j + 1] = xr1[j]; }
      if (j == 8)   { inps[2 * kHin] = s0; inps[2 * kHin + 1] = s1; }
      if (j == 0) {
        stor[(size_t)n0 * kL + t + 1] = s0;
        stor[(size_t)n1 * kL + t + 1] = s1;
      }
    }
    __syncthreads();  // barrier B: next-step inp fully staged
  }
}

extern "C" void kernel_launch(void* const* d_in, const int* in_sizes, int n_in,
                              void* d_out, int out_size, void* d_ws, size_t ws_size,
                              hipStream_t stream) {
  const float* x  = (const float*)d_in[0];
  const float* W1 = (const float*)d_in[1];
  const float* b1 = (const float*)d_in[2];
  const float* W2 = (const float*)d_in[3];
  const float* b2 = (const float*)d_in[4];
  float* out = (float*)d_out;

  dim3 grid(kN / kBpb);   // 128 blocks, 1 per CU on 128 of 256 CUs
  dim3 block(kBlk);       // 512 threads = 8 waves
  hipLaunchKernelGGL(resrnn_fwd, grid, block, 0, stream, x, W1, b1, W2, b2, out);
}

// Round 3
// 27460.052 us; speedup vs baseline: 1.0794x; 1.0794x over previous
//
#include <hip/hip_runtime.h>
#include <math.h>

// resRNN forward: N=256, L=1024, inp=521 (=8 x + 1 storage + 512 hx), HID=512, OUT=1.
// Round 3: same residency design as round 2 (W1 rows in VGPR + LDS, remainder
// streamed from L2 with depth-4 prefetch), but with the spill fixed:
//  - amdgpu_waves_per_eu(2,2) pins occupancy at 2 waves/EU -> 256-VGPR budget
//    (round 2's launch_bounds let the allocator target 4 waves/EU = 128 VGPRs,
//    spilling wreg[] to scratch: FETCH_SIZE 31 MB -> 35 GB, 2.5x regression).
//  - asm volatile "+v" pin after the wreg fill forces the weights to live in
//    VGPRs and blocks rematerialization of the global loads into the t-loop.
//  - RREG 160->124 (est. peak live ~190 regs), RLDS 72->76 (159.9 KB LDS).
// Partition: rows [0,124) VGPR, [124,200) LDS, [200,520) streamed (40 chunks
// of 8), row 520 tail. Streamed bytes/step/CU: 1.07 MB -> 642 KB.

constexpr int kN   = 256;
constexpr int kL   = 1024;
constexpr int kHin = 8;
constexpr int kHid = 512;
constexpr int kInp = kHin + 1 + kHid;        // 521
constexpr int kBlk = 512;                    // threads per block
constexpr int kBpb = 2;                      // batch elements per block

constexpr int RREG = 124;                    // W1 rows resident in VGPRs
constexpr int RLDS = 76;                     // W1 rows resident in LDS (152 KB)
constexpr int RRES = RREG + RLDS;            // 200 resident rows
constexpr int NCH  = (kInp - 1 - RRES) / 8;  // 40 streamed chunks of 8 rows (+1 tail)
static_assert(NCH % 4 == 0, "depth-4 rotation needs NCH % 4 == 0");
static_assert(RRES + 8 * NCH + 1 == kInp, "row partition must cover 521 rows");

// Consume 8 streamed rows starting at row kb using weight buffer WB[0..7].
#define CONSUME8(kb, WB)                                                         \
  {                                                                              \
    const float4 va = *reinterpret_cast<const float4*>(&inps[2 * (kb)]);         \
    const float4 vb = *reinterpret_cast<const float4*>(&inps[2 * (kb) + 4]);     \
    const float4 vc = *reinterpret_cast<const float4*>(&inps[2 * (kb) + 8]);     \
    const float4 vd = *reinterpret_cast<const float4*>(&inps[2 * (kb) + 12]);    \
    a0 = fmaf(va.x, (WB)[0], a0); a1 = fmaf(va.y, (WB)[0], a1);                  \
    c0 = fmaf(va.z, (WB)[1], c0); c1 = fmaf(va.w, (WB)[1], c1);                  \
    a0 = fmaf(vb.x, (WB)[2], a0); a1 = fmaf(vb.y, (WB)[2], a1);                  \
    c0 = fmaf(vb.z, (WB)[3], c0); c1 = fmaf(vb.w, (WB)[3], c1);                  \
    a0 = fmaf(vc.x, (WB)[4], a0); a1 = fmaf(vc.y, (WB)[4], a1);                  \
    c0 = fmaf(vc.z, (WB)[5], c0); c1 = fmaf(vc.w, (WB)[5], c1);                  \
    a0 = fmaf(vd.x, (WB)[6], a0); a1 = fmaf(vd.y, (WB)[6], a1);                  \
    c0 = fmaf(vd.z, (WB)[7], c0); c1 = fmaf(vd.w, (WB)[7], c1);                  \
  }

// Load streamed chunk ch (8 rows) into buf[0..7]; coalesced column reads.
#define LOAD8(buf, ch)                                                           \
  {                                                                              \
    const float* _p = wstr + (size_t)(8 * (ch)) * kHid;                          \
    (buf)[0] = _p[0 * kHid]; (buf)[1] = _p[1 * kHid];                            \
    (buf)[2] = _p[2 * kHid]; (buf)[3] = _p[3 * kHid];                            \
    (buf)[4] = _p[4 * kHid]; (buf)[5] = _p[5 * kHid];                            \
    (buf)[6] = _p[6 * kHid]; (buf)[7] = _p[7 * kHid];                            \
  }

__global__
__attribute__((amdgpu_flat_work_group_size(kBlk, kBlk)))
__attribute__((amdgpu_waves_per_eu(2, 2)))
void resrnn_fwd(const float* __restrict__ x, const float* __restrict__ W1,
                const float* __restrict__ b1, const float* __restrict__ W2,
                const float* __restrict__ b2, float* __restrict__ out) {
  // inps: interleaved pairs {batch0[k], batch1[k]} for k in [0,521)
  __shared__ __align__(16) float inps[2 * kInp + 2];
  __shared__ float wlds[RLDS][kHid];   // W1 rows [RREG, RRES), 152 KB
  __shared__ float red[8][2];

  const int j  = threadIdx.x;          // hidden column 0..511
  const int n0 = blockIdx.x * kBpb;
  const int n1 = n0 + 1;

  const float b2v = b2[0];
  const float w2j = W2[j];
  const float b1j = b1[j];

  float* const outp = out;                        // (N,L,1) flat
  float* const stor = out + (size_t)kN * kL;      // implied_storage

  const float* x0 = x + (size_t)n0 * kL * kHin;
  const float* x1 = x + (size_t)n1 * kL * kHin;

  const float* const wj   = W1 + j;               // column j, stride kHid
  const float* const wstr = wj + (size_t)RRES * kHid;

  // ---- one-time W1 cache fill ----
  float wreg[RREG];
  #pragma unroll
  for (int r = 0; r < RREG; ++r) wreg[r] = wj[(size_t)r * kHid];
  // Pin to VGPRs: forbids remat of the loads into the t-loop and demotion to
  // scratch (round-2 failure mode).
  #pragma unroll
  for (int r = 0; r < RREG; ++r) asm volatile("" : "+v"(wreg[r]));
  for (int r = 0; r < RLDS; ++r) wlds[r][j] = wj[(size_t)(RREG + r) * kHid];

  // ---- init: hx = 0, s_0 = x_0[0] ----
  {
    float2 z; z.x = 0.f; z.y = 0.f;
    *reinterpret_cast<float2*>(&inps[2 * (kHin + 1 + j)]) = z;
  }
  float s0 = x0[0];
  float s1 = x1[0];
  if (j < kHin) { inps[2 * j] = x0[j]; inps[2 * j + 1] = x1[j]; }
  if (j == 8)   { inps[2 * kHin] = s0; inps[2 * kHin + 1] = s1; }
  if (j == 0) {
    stor[(size_t)n0 * kL] = s0;
    stor[(size_t)n1 * kL] = s1;
  }
  __syncthreads();

  for (int t = 0; t < kL; ++t) {
    float a0 = b1j, a1 = b1j;   // fma chain A (even rows)
    float c0 = 0.f, c1 = 0.f;   // fma chain B (odd rows)

    // issue first 4 streamed chunks + tail row early (hide L2 latency under
    // the resident-row FMA phases below)
    float bA[8], bB[8], bC[8], bD[8];
    LOAD8(bA, 0) LOAD8(bB, 1) LOAD8(bC, 2) LOAD8(bD, 3)
    const float wtail = wj[(size_t)(kInp - 1) * kHid];

    // ---- rows [0, RREG): weights in VGPRs, inputs via LDS broadcast ----
    #pragma unroll
    for (int k = 0; k < RREG; k += 2) {
      const float4 v = *reinterpret_cast<const float4*>(&inps[2 * k]);
      a0 = fmaf(v.x, wreg[k], a0);     a1 = fmaf(v.y, wreg[k], a1);
      c0 = fmaf(v.z, wreg[k + 1], c0); c1 = fmaf(v.w, wreg[k + 1], c1);
    }

    // ---- rows [RREG, RRES): weights in LDS (lane-consecutive, conflict-free) ----
    #pragma unroll 4
    for (int k = 0; k < RLDS; k += 2) {
      const float4 v = *reinterpret_cast<const float4*>(&inps[2 * (RREG + k)]);
      const float wa = wlds[k][j];
      const float wb = wlds[k + 1][j];
      a0 = fmaf(v.x, wa, a0); a1 = fmaf(v.y, wa, a1);
      c0 = fmaf(v.z, wb, c0); c1 = fmaf(v.w, wb, c1);
    }

    // ---- rows [RRES, 520): streamed from L2, depth-4 rolling prefetch ----
    #pragma unroll 1
    for (int cc = 0; cc < NCH / 4; ++cc) {
      const int ch = 4 * cc;
      CONSUME8(RRES + 8 * (ch + 0), bA)
      if (cc < NCH / 4 - 1) { LOAD8(bA, ch + 4) }
      CONSUME8(RRES + 8 * (ch + 1), bB)
      if (cc < NCH / 4 - 1) { LOAD8(bB, ch + 5) }
      CONSUME8(RRES + 8 * (ch + 2), bC)
      if (cc < NCH / 4 - 1) { LOAD8(bC, ch + 6) }
      CONSUME8(RRES + 8 * (ch + 3), bD)
      if (cc < NCH / 4 - 1) { LOAD8(bD, ch + 7) }
    }
    {  // tail row k = 520
      const float2 v = *reinterpret_cast<const float2*>(&inps[2 * (kInp - 1)]);
      a0 = fmaf(v.x, wtail, a0);
      a1 = fmaf(v.y, wtail, a1);
    }

    const float h0 = tanhf(a0 + c0);
    const float h1 = tanhf(a1 + c1);

    // ---- out = hx_new . W2 + b2 : wave shuffle reduce, then LDS combine ----
    float p0 = h0 * w2j;
    float p1 = h1 * w2j;
    #pragma unroll
    for (int off = 32; off > 0; off >>= 1) {
      p0 += __shfl_down(p0, off, 64);
      p1 += __shfl_down(p1, off, 64);
    }
    const int lane = j & 63, wid = j >> 6;
    if (lane == 0) { red[wid][0] = p0; red[wid][1] = p1; }
    __syncthreads();  // barrier A: all inps reads done; red[] populated

    float d0 = 0.f, d1 = 0.f;
    #pragma unroll
    for (int q = 0; q < 8; ++q) { d0 += red[q][0]; d1 += red[q][1]; }
    const float o0 = d0 + b2v;  // identical in every thread
    const float o1 = d1 + b2v;
    if (j == 0) {
      outp[(size_t)n0 * kL + t] = o0;
      outp[(size_t)n1 * kL + t] = o1;
    }

    // ---- stage step t+1: hx, x, s = s + x_{t+1}[0] - out_t ----
    {
      float2 hv; hv.x = h0; hv.y = h1;
      *reinterpret_cast<float2*>(&inps[2 * (kHin + 1 + j)]) = hv;
    }
    if (t + 1 < kL) {
      const float* xr0 = x0 + (size_t)(t + 1) * kHin;
      const float* xr1 = x1 + (size_t)(t + 1) * kHin;
      s0 += xr0[0] - o0;  // replicated identically across threads
      s1 += xr1[0] - o1;
      if (j < kHin) { inps[2 * j] = xr0[j]; inps[2 * j + 1] = xr1[j]; }
      if (j == 8)   { inps[2 * kHin] = s0; inps[2 * kHin + 1] = s1; }
      if (j == 0) {
        stor[(size_t)n0 * kL + t + 1] = s0;
        stor[(size_t)n1 * kL + t + 1] = s1;
      }
    }
    __syncthreads();  // barrier B: next-step inp fully staged
  }
}

extern "C" void kernel_launch(void* const* d_in, const int* in_sizes, int n_in,
                              void* d_out, int out_size, void* d_ws, size_t ws_size,
                              hipStream_t stream) {
  const float* x  = (const float*)d_in[0];
  const float* W1 = (const float*)d_in[1];
  const float* b1 = (const float*)d_in[2];
  const float* W2 = (const float*)d_in[3];
  const float* b2 = (const float*)d_in[4];
  float* out = (float*)d_out;

  dim3 grid(kN / kBpb);   // 128 blocks, 1 per CU on 128 of 256 CUs
  dim3 block(kBlk);       // 512 threads = 8 waves
  hipLaunchKernelGGL(resrnn_fwd, grid, block, 0, stream, x, W1, b1, W2, b2, out);
}

// Round 4
// 14924.994 us; speedup vs baseline: 1.9859x; 1.8399x over previous
//
#include <hip/hip_runtime.h>
#include <math.h>

// resRNN forward: N=256, L=1024, inp=521 (=8 x + 1 storage + 512 hx), HID=512, OUT=1.
// Round 4: same residency partition as round 3, but the register-resident W1
// rows live in AGPRs via explicit v_accvgpr_write/read inline asm.
// Why: rounds 2-3 both allocated EXACTLY 128 arch VGPRs (under two different
// occupancy attributes) and spilled wreg[] to scratch (FETCH_SIZE 26-35 GB of
// per-step reloads). On the gfx950 unified RF the 256-reg/wave budget is split
// arch/accum; the accum half was idle. We claim it explicitly:
//   fill:  asm v_accvgpr_write_b32 (once, before t-loop)
//   use:   asm volatile v_accvgpr_read_b32 (per step; volatile so reads are
//          not CSE/hoisted into 124 live VGPR copies, recreating the spill)
// Partition: rows [0,124) AGPR, [124,200) LDS (152 KB), [200,520) streamed
// (40 chunks of 8, depth-4 rolling prefetch), row 520 tail.
// Streamed bytes/step/CU: 1.07 MB -> 640 KB.

constexpr int kN   = 256;
constexpr int kL   = 1024;
constexpr int kHin = 8;
constexpr int kHid = 512;
constexpr int kInp = kHin + 1 + kHid;        // 521
constexpr int kBlk = 512;                    // threads per block
constexpr int kBpb = 2;                      // batch elements per block

constexpr int RAGP = 124;                    // W1 rows resident in AGPRs
constexpr int RLDS = 76;                     // W1 rows resident in LDS (152 KB)
constexpr int RRES = RAGP + RLDS;            // 200 resident rows
constexpr int NCH  = (kInp - 1 - RRES) / 8;  // 40 streamed chunks of 8 rows (+1 tail)
static_assert(NCH % 4 == 0, "depth-4 rotation needs NCH % 4 == 0");
static_assert(RRES + 8 * NCH + 1 == kInp, "row partition must cover 521 rows");

// Consume 8 streamed rows starting at row kb using weight buffer WB[0..7].
#define CONSUME8(kb, WB)                                                         \
  {                                                                              \
    const float4 va = *reinterpret_cast<const float4*>(&inps[2 * (kb)]);         \
    const float4 vb = *reinterpret_cast<const float4*>(&inps[2 * (kb) + 4]);     \
    const float4 vc = *reinterpret_cast<const float4*>(&inps[2 * (kb) + 8]);     \
    const float4 vd = *reinterpret_cast<const float4*>(&inps[2 * (kb) + 12]);    \
    a0 = fmaf(va.x, (WB)[0], a0); a1 = fmaf(va.y, (WB)[0], a1);                  \
    c0 = fmaf(va.z, (WB)[1], c0); c1 = fmaf(va.w, (WB)[1], c1);                  \
    a0 = fmaf(vb.x, (WB)[2], a0); a1 = fmaf(vb.y, (WB)[2], a1);                  \
    c0 = fmaf(vb.z, (WB)[3], c0); c1 = fmaf(vb.w, (WB)[3], c1);                  \
    a0 = fmaf(vc.x, (WB)[4], a0); a1 = fmaf(vc.y, (WB)[4], a1);                  \
    c0 = fmaf(vc.z, (WB)[5], c0); c1 = fmaf(vc.w, (WB)[5], c1);                  \
    a0 = fmaf(vd.x, (WB)[6], a0); a1 = fmaf(vd.y, (WB)[6], a1);                  \
    c0 = fmaf(vd.z, (WB)[7], c0); c1 = fmaf(vd.w, (WB)[7], c1);                  \
  }

// Load streamed chunk ch (8 rows) into buf[0..7]; coalesced column reads.
#define LOAD8(buf, ch)                                                           \
  {                                                                              \
    const float* _p = wstr + (size_t)(8 * (ch)) * kHid;                          \
    (buf)[0] = _p[0 * kHid]; (buf)[1] = _p[1 * kHid];                            \
    (buf)[2] = _p[2 * kHid]; (buf)[3] = _p[3 * kHid];                            \
    (buf)[4] = _p[4 * kHid]; (buf)[5] = _p[5 * kHid];                            \
    (buf)[6] = _p[6 * kHid]; (buf)[7] = _p[7 * kHid];                            \
  }

__global__
__attribute__((amdgpu_flat_work_group_size(kBlk, kBlk)))
__attribute__((amdgpu_waves_per_eu(2, 2)))
void resrnn_fwd(const float* __restrict__ x, const float* __restrict__ W1,
                const float* __restrict__ b1, const float* __restrict__ W2,
                const float* __restrict__ b2, float* __restrict__ out) {
  // inps: interleaved pairs {batch0[k], batch1[k]} for k in [0,521)
  __shared__ __align__(16) float inps[2 * kInp + 2];
  __shared__ float wlds[RLDS][kHid];   // W1 rows [RAGP, RRES), 152 KB
  __shared__ float red[8][2];

  const int j  = threadIdx.x;          // hidden column 0..511
  const int n0 = blockIdx.x * kBpb;
  const int n1 = n0 + 1;

  const float b2v = b2[0];
  const float w2j = W2[j];
  const float b1j = b1[j];

  float* const outp = out;                        // (N,L,1) flat
  float* const stor = out + (size_t)kN * kL;      // implied_storage

  const float* x0 = x + (size_t)n0 * kL * kHin;
  const float* x1 = x + (size_t)n1 * kL * kHin;

  const float* const wj   = W1 + j;               // column j, stride kHid
  const float* const wstr = wj + (size_t)RRES * kHid;

  // ---- one-time W1 cache fill: rows [0,RAGP) -> AGPRs ----
  float areg[RAGP];  // each element lives in an AGPR (asm "a" class)
  #pragma unroll
  for (int r = 0; r < RAGP; ++r) {
    const float v = wj[(size_t)r * kHid];
    asm volatile("v_accvgpr_write_b32 %0, %1" : "=a"(areg[r]) : "v"(v));
  }
  // rows [RAGP, RRES) -> LDS
  for (int r = 0; r < RLDS; ++r) wlds[r][j] = wj[(size_t)(RAGP + r) * kHid];
  // tail row 520 -> one arch VGPR, loaded once (round 3 reloaded it per step)
  float wtail = wj[(size_t)(kInp - 1) * kHid];
  asm volatile("" : "+v"(wtail));

  // ---- init: hx = 0, s_0 = x_0[0] ----
  {
    float2 z; z.x = 0.f; z.y = 0.f;
    *reinterpret_cast<float2*>(&inps[2 * (kHin + 1 + j)]) = z;
  }
  float s0 = x0[0];
  float s1 = x1[0];
  if (j < kHin) { inps[2 * j] = x0[j]; inps[2 * j + 1] = x1[j]; }
  if (j == 8)   { inps[2 * kHin] = s0; inps[2 * kHin + 1] = s1; }
  if (j == 0) {
    stor[(size_t)n0 * kL] = s0;
    stor[(size_t)n1 * kL] = s1;
  }
  __syncthreads();

  for (int t = 0; t < kL; ++t) {
    float a0 = b1j, a1 = b1j;   // fma chain A (even rows)
    float c0 = 0.f, c1 = 0.f;   // fma chain B (odd rows)

    // issue first 4 streamed chunks early (hide L2 latency under the
    // resident-row FMA phases below)
    float bA[8], bB[8], bC[8], bD[8];
    LOAD8(bA, 0) LOAD8(bB, 1) LOAD8(bC, 2) LOAD8(bD, 3)

    // ---- rows [0, RAGP): weights in AGPRs, inputs via LDS broadcast ----
    #pragma unroll
    for (int k = 0; k < RAGP; k += 2) {
      const float4 v = *reinterpret_cast<const float4*>(&inps[2 * k]);
      float w0, w1;
      asm volatile("v_accvgpr_read_b32 %0, %1" : "=v"(w0) : "a"(areg[k]));
      asm volatile("v_accvgpr_read_b32 %0, %1" : "=v"(w1) : "a"(areg[k + 1]));
      a0 = fmaf(v.x, w0, a0); a1 = fmaf(v.y, w0, a1);
      c0 = fmaf(v.z, w1, c0); c1 = fmaf(v.w, w1, c1);
    }

    // ---- rows [RAGP, RRES): weights in LDS (lane-consecutive, 2-way = free) ----
    #pragma unroll 4
    for (int k = 0; k < RLDS; k += 2) {
      const float4 v = *reinterpret_cast<const float4*>(&inps[2 * (RAGP + k)]);
      const float wa = wlds[k][j];
      const float wb = wlds[k + 1][j];
      a0 = fmaf(v.x, wa, a0); a1 = fmaf(v.y, wa, a1);
      c0 = fmaf(v.z, wb, c0); c1 = fmaf(v.w, wb, c1);
    }

    // ---- rows [RRES, 520): streamed from L2, depth-4 rolling prefetch ----
    #pragma unroll 1
    for (int cc = 0; cc < NCH / 4; ++cc) {
      const int ch = 4 * cc;
      CONSUME8(RRES + 8 * (ch + 0), bA)
      if (cc < NCH / 4 - 1) { LOAD8(bA, ch + 4) }
      CONSUME8(RRES + 8 * (ch + 1), bB)
      if (cc < NCH / 4 - 1) { LOAD8(bB, ch + 5) }
      CONSUME8(RRES + 8 * (ch + 2), bC)
      if (cc < NCH / 4 - 1) { LOAD8(bC, ch + 6) }
      CONSUME8(RRES + 8 * (ch + 3), bD)
      if (cc < NCH / 4 - 1) { LOAD8(bD, ch + 7) }
    }
    {  // tail row k = 520
      const float2 v = *reinterpret_cast<const float2*>(&inps[2 * (kInp - 1)]);
      a0 = fmaf(v.x, wtail, a0);
      a1 = fmaf(v.y, wtail, a1);
    }

    const float h0 = tanhf(a0 + c0);
    const float h1 = tanhf(a1 + c1);

    // ---- out = hx_new . W2 + b2 : wave shuffle reduce, then LDS combine ----
    float p0 = h0 * w2j;
    float p1 = h1 * w2j;
    #pragma unroll
    for (int off = 32; off > 0; off >>= 1) {
      p0 += __shfl_down(p0, off, 64);
      p1 += __shfl_down(p1, off, 64);
    }
    const int lane = j & 63, wid = j >> 6;
    if (lane == 0) { red[wid][0] = p0; red[wid][1] = p1; }
    __syncthreads();  // barrier A: all inps reads done; red[] populated

    float d0 = 0.f, d1 = 0.f;
    #pragma unroll
    for (int q = 0; q < 8; ++q) { d0 += red[q][0]; d1 += red[q][1]; }
    const float o0 = d0 + b2v;  // identical in every thread
    const float o1 = d1 + b2v;
    if (j == 0) {
      outp[(size_t)n0 * kL + t] = o0;
      outp[(size_t)n1 * kL + t] = o1;
    }

    // ---- stage step t+1: hx, x, s = s + x_{t+1}[0] - out_t ----
    {
      float2 hv; hv.x = h0; hv.y = h1;
      *reinterpret_cast<float2*>(&inps[2 * (kHin + 1 + j)]) = hv;
    }
    if (t + 1 < kL) {
      const float* xr0 = x0 + (size_t)(t + 1) * kHin;
      const float* xr1 = x1 + (size_t)(t + 1) * kHin;
      s0 += xr0[0] - o0;  // replicated identically across threads
      s1 += xr1[0] - o1;
      if (j < kHin) { inps[2 * j] = xr0[j]; inps[2 * j + 1] = xr1[j]; }
      if (j == 8)   { inps[2 * kHin] = s0; inps[2 * kHin + 1] = s1; }
      if (j == 0) {
        stor[(size_t)n0 * kL + t + 1] = s0;
        stor[(size_t)n1 * kL + t + 1] = s1;
      }
    }
    __syncthreads();  // barrier B: next-step inp fully staged
  }
}

extern "C" void kernel_launch(void* const* d_in, const int* in_sizes, int n_in,
                              void* d_out, int out_size, void* d_ws, size_t ws_size,
                              hipStream_t stream) {
  const float* x  = (const float*)d_in[0];
  const float* W1 = (const float*)d_in[1];
  const float* b1 = (const float*)d_in[2];
  const float* W2 = (const float*)d_in[3];
  const float* b2 = (const float*)d_in[4];
  float* out = (float*)d_out;

  dim3 grid(kN / kBpb);   // 128 blocks, 1 per CU on 128 of 256 CUs
  dim3 block(kBlk);       // 512 threads = 8 waves
  hipLaunchKernelGGL(resrnn_fwd, grid, block, 0, stream, x, W1, b1, W2, b2, out);
}

// Round 5
// 13235.202 us; speedup vs baseline: 2.2395x; 1.1277x over previous
//
#include <hip/hip_runtime.h>
#include <math.h>

// resRNN forward: N=256, L=1024, inp=521 (=8 x + 1 storage + 512 hx), HID=512, OUT=1.
// Round 5: residency partition as round 4 (AGPR + LDS + L2-stream), with the two
// measured stalls fixed:
//  (a) streamed W1 rows repacked (one-time kernel) into [chunk][col][4] so each
//      thread issues ONE dwordx4 per 4 rows instead of 4 scalar dwords ->
//      4x bytes in flight at equal issue rate (round 4 was issue-limited at
//      19 B/cyc/CU; port bound is ~56).
//  (b) AGPR reads batched 8-per-volatile-asm-block (16 blocks/step vs 124),
//      with next-group inps loads issued before each block so ds_read latency
//      hides under the previous group's FMAs. Round 4's per-row volatile asm
//      serialized ~7K cyc/step of LDS latency.
// Partition: rows [0,128) AGPR, [128,204) LDS (152 KB), [204,520) streamed
// packed (79 chunks of 4 rows), row 520 tail VGPR.

constexpr int kN   = 256;
constexpr int kL   = 1024;
constexpr int kHin = 8;
constexpr int kHid = 512;
constexpr int kInp = kHin + 1 + kHid;        // 521
constexpr int kBlk = 512;
constexpr int kBpb = 2;

constexpr int RAGP  = 128;                   // W1 rows resident in AGPRs
constexpr int NAGRP = RAGP / 8;              // 16 groups of 8 rows
constexpr int RLDS  = 76;                    // W1 rows resident in LDS (152 KB)
constexpr int RRES  = RAGP + RLDS;           // 204 resident rows
constexpr int NPK   = (kInp - 1 - RRES) / 4; // 79 packed chunks of 4 streamed rows
static_assert(RRES + 4 * NPK + 1 == kInp, "row partition must cover 521 rows");

// Packed streamed weights: g_w1p[(c*512 + j)*4 + i] = W1[RRES + 4c + i][j].
__device__ __align__(16) float g_w1p[NPK * kHid * 4];

__global__ void repack_w1(const float* __restrict__ W1) {
  const int idx = blockIdx.x * 256 + threadIdx.x;
  if (idx >= NPK * kHid) return;
  const int c = idx >> 9;          // chunk
  const int j = idx & (kHid - 1);  // column
  const int r = RRES + 4 * c;
  float4 v;
  v.x = W1[(size_t)(r + 0) * kHid + j];
  v.y = W1[(size_t)(r + 1) * kHid + j];
  v.z = W1[(size_t)(r + 2) * kHid + j];
  v.w = W1[(size_t)(r + 3) * kHid + j];
  *reinterpret_cast<float4*>(&g_w1p[(size_t)idx * 4]) = v;
}

__global__
__attribute__((amdgpu_flat_work_group_size(kBlk, kBlk)))
__attribute__((amdgpu_waves_per_eu(2, 2)))
void resrnn_fwd(const float* __restrict__ x, const float* __restrict__ W1,
                const float* __restrict__ b1, const float* __restrict__ W2,
                const float* __restrict__ b2, float* __restrict__ out) {
  // inps: interleaved pairs {batch0[k], batch1[k]} for k in [0,521)
  __shared__ __align__(16) float inps[2 * kInp + 2];
  __shared__ float wlds[RLDS][kHid];   // W1 rows [RAGP, RRES), 152 KB
  __shared__ float red[8][2];

  const int j  = threadIdx.x;          // hidden column 0..511
  const int n0 = blockIdx.x * kBpb;
  const int n1 = n0 + 1;

  const float b2v = b2[0];
  const float w2j = W2[j];
  const float b1j = b1[j];

  float* const outp = out;                        // (N,L,1) flat
  float* const stor = out + (size_t)kN * kL;      // implied_storage

  const float* x0 = x + (size_t)n0 * kL * kHin;
  const float* x1 = x + (size_t)n1 * kL * kHin;

  const float* const wj  = W1 + j;                // column j, stride kHid
  const float* const wpk = g_w1p + (size_t)j * 4; // packed streamed, stride 2048 floats

  // ---- one-time W1 cache fill: rows [0,RAGP) -> AGPRs ----
  float areg[RAGP];
  #pragma unroll
  for (int r = 0; r < RAGP; ++r) {
    const float v = wj[(size_t)r * kHid];
    asm volatile("v_accvgpr_write_b32 %0, %1" : "=a"(areg[r]) : "v"(v));
  }
  // rows [RAGP, RRES) -> LDS
  for (int r = 0; r < RLDS; ++r) wlds[r][j] = wj[(size_t)(RAGP + r) * kHid];
  // tail row 520 -> one arch VGPR, loaded once
  float wtail = wj[(size_t)(kInp - 1) * kHid];
  asm volatile("" : "+v"(wtail));

  // ---- init: hx = 0, s_0 = x_0[0] ----
  {
    float2 z; z.x = 0.f; z.y = 0.f;
    *reinterpret_cast<float2*>(&inps[2 * (kHin + 1 + j)]) = z;
  }
  float s0 = x0[0];
  float s1 = x1[0];
  if (j < kHin) { inps[2 * j] = x0[j]; inps[2 * j + 1] = x1[j]; }
  if (j == 8)   { inps[2 * kHin] = s0; inps[2 * kHin + 1] = s1; }
  if (j == 0) {
    stor[(size_t)n0 * kL] = s0;
    stor[(size_t)n1 * kL] = s1;
  }
  __syncthreads();

  for (int t = 0; t < kL; ++t) {
    float a0 = b1j, a1 = b1j;   // fma chain A (even rows)
    float c0 = 0.f, c1 = 0.f;   // fma chain B (odd rows)

    // ---- rows [0, RAGP): weights in AGPRs; 16 groups of 8 rows.
    // Inputs for group g+1 are loaded BEFORE group g's volatile asm block so
    // ds_read latency hides under the previous group's reads+FMAs.
    float4 nx0 = *reinterpret_cast<const float4*>(&inps[0]);
    float4 nx1 = *reinterpret_cast<const float4*>(&inps[4]);
    float4 nx2 = *reinterpret_cast<const float4*>(&inps[8]);
    float4 nx3 = *reinterpret_cast<const float4*>(&inps[12]);
    #pragma unroll
    for (int g = 0; g < NAGRP; ++g) {
      const float4 u0 = nx0, u1 = nx1, u2 = nx2, u3 = nx3;
      if (g + 1 < NAGRP) {
        nx0 = *reinterpret_cast<const float4*>(&inps[16 * (g + 1)]);
        nx1 = *reinterpret_cast<const float4*>(&inps[16 * (g + 1) + 4]);
        nx2 = *reinterpret_cast<const float4*>(&inps[16 * (g + 1) + 8]);
        nx3 = *reinterpret_cast<const float4*>(&inps[16 * (g + 1) + 12]);
      }
      float w0, w1, w2, w3, w4, w5, w6, w7;
      asm volatile(
          "v_accvgpr_read_b32 %0, %8\n\t"
          "v_accvgpr_read_b32 %1, %9\n\t"
          "v_accvgpr_read_b32 %2, %10\n\t"
          "v_accvgpr_read_b32 %3, %11\n\t"
          "v_accvgpr_read_b32 %4, %12\n\t"
          "v_accvgpr_read_b32 %5, %13\n\t"
          "v_accvgpr_read_b32 %6, %14\n\t"
          "v_accvgpr_read_b32 %7, %15"
          : "=v"(w0), "=v"(w1), "=v"(w2), "=v"(w3),
            "=v"(w4), "=v"(w5), "=v"(w6), "=v"(w7)
          : "a"(areg[8 * g + 0]), "a"(areg[8 * g + 1]),
            "a"(areg[8 * g + 2]), "a"(areg[8 * g + 3]),
            "a"(areg[8 * g + 4]), "a"(areg[8 * g + 5]),
            "a"(areg[8 * g + 6]), "a"(areg[8 * g + 7]));
      a0 = fmaf(u0.x, w0, a0); a1 = fmaf(u0.y, w0, a1);
      c0 = fmaf(u0.z, w1, c0); c1 = fmaf(u0.w, w1, c1);
      a0 = fmaf(u1.x, w2, a0); a1 = fmaf(u1.y, w2, a1);
      c0 = fmaf(u1.z, w3, c0); c1 = fmaf(u1.w, w3, c1);
      a0 = fmaf(u2.x, w4, a0); a1 = fmaf(u2.y, w4, a1);
      c0 = fmaf(u2.z, w5, c0); c1 = fmaf(u2.w, w5, c1);
      a0 = fmaf(u3.x, w6, a0); a1 = fmaf(u3.y, w6, a1);
      c0 = fmaf(u3.z, w7, c0); c1 = fmaf(u3.w, w7, c1);
    }

    // ---- rows [RAGP, RRES): weights in LDS (lane-consecutive, conflict-free) ----
    #pragma unroll 4
    for (int k = 0; k < RLDS; k += 2) {
      const float4 v = *reinterpret_cast<const float4*>(&inps[2 * (RAGP + k)]);
      const float wa = wlds[k][j];
      const float wb = wlds[k + 1][j];
      a0 = fmaf(v.x, wa, a0); a1 = fmaf(v.y, wa, a1);
      c0 = fmaf(v.z, wb, c0); c1 = fmaf(v.w, wb, c1);
    }

    // ---- rows [RRES, 520): streamed packed from L2, one dwordx4 per 4 rows ----
    #pragma unroll 8
    for (int c = 0; c < NPK; ++c) {
      const float4 wv = *reinterpret_cast<const float4*>(&wpk[(size_t)c * kHid * 4]);
      const int kb = RRES + 4 * c;
      const float4 va = *reinterpret_cast<const float4*>(&inps[2 * kb]);
      const float4 vb = *reinterpret_cast<const float4*>(&inps[2 * kb + 4]);
      a0 = fmaf(va.x, wv.x, a0); a1 = fmaf(va.y, wv.x, a1);
      c0 = fmaf(va.z, wv.y, c0); c1 = fmaf(va.w, wv.y, c1);
      a0 = fmaf(vb.x, wv.z, a0); a1 = fmaf(vb.y, wv.z, a1);
      c0 = fmaf(vb.z, wv.w, c0); c1 = fmaf(vb.w, wv.w, c1);
    }
    {  // tail row k = 520
      const float2 v = *reinterpret_cast<const float2*>(&inps[2 * (kInp - 1)]);
      a0 = fmaf(v.x, wtail, a0);
      a1 = fmaf(v.y, wtail, a1);
    }

    const float h0 = tanhf(a0 + c0);
    const float h1 = tanhf(a1 + c1);

    // ---- out = hx_new . W2 + b2 : wave shuffle reduce, then LDS combine ----
    float p0 = h0 * w2j;
    float p1 = h1 * w2j;
    #pragma unroll
    for (int off = 32; off > 0; off >>= 1) {
      p0 += __shfl_down(p0, off, 64);
      p1 += __shfl_down(p1, off, 64);
    }
    const int lane = j & 63, wid = j >> 6;
    if (lane == 0) { red[wid][0] = p0; red[wid][1] = p1; }
    __syncthreads();  // barrier A: all inps reads done; red[] populated

    float d0 = 0.f, d1 = 0.f;
    #pragma unroll
    for (int q = 0; q < 8; ++q) { d0 += red[q][0]; d1 += red[q][1]; }
    const float o0 = d0 + b2v;  // identical in every thread
    const float o1 = d1 + b2v;
    if (j == 0) {
      outp[(size_t)n0 * kL + t] = o0;
      outp[(size_t)n1 * kL + t] = o1;
    }

    // ---- stage step t+1: hx, x, s = s + x_{t+1}[0] - out_t ----
    {
      float2 hv; hv.x = h0; hv.y = h1;
      *reinterpret_cast<float2*>(&inps[2 * (kHin + 1 + j)]) = hv;
    }
    if (t + 1 < kL) {
      const float* xr0 = x0 + (size_t)(t + 1) * kHin;
      const float* xr1 = x1 + (size_t)(t + 1) * kHin;
      s0 += xr0[0] - o0;  // replicated identically across threads
      s1 += xr1[0] - o1;
      if (j < kHin) { inps[2 * j] = xr0[j]; inps[2 * j + 1] = xr1[j]; }
      if (j == 8)   { inps[2 * kHin] = s0; inps[2 * kHin + 1] = s1; }
      if (j == 0) {
        stor[(size_t)n0 * kL + t + 1] = s0;
        stor[(size_t)n1 * kL + t + 1] = s1;
      }
    }
    __syncthreads();  // barrier B: next-step inp fully staged
  }
}

extern "C" void kernel_launch(void* const* d_in, const int* in_sizes, int n_in,
                              void* d_out, int out_size, void* d_ws, size_t ws_size,
                              hipStream_t stream) {
  const float* x  = (const float*)d_in[0];
  const float* W1 = (const float*)d_in[1];
  const float* b1 = (const float*)d_in[2];
  const float* W2 = (const float*)d_in[3];
  const float* b2 = (const float*)d_in[4];
  float* out = (float*)d_out;

  // one-time (per launch) repack of streamed W1 rows into float4-per-thread form
  {
    const int total = NPK * kHid;                 // 40448
    dim3 g((total + 255) / 256), b(256);
    hipLaunchKernelGGL(repack_w1, g, b, 0, stream, W1);
  }

  dim3 grid(kN / kBpb);   // 128 blocks, 1 per CU on 128 of 256 CUs
  dim3 block(kBlk);       // 512 threads = 8 waves
  hipLaunchKernelGGL(resrnn_fwd, grid, block, 0, stream, x, W1, b1, W2, b2, out);
}

// Round 6
// 7427.667 us; speedup vs baseline: 3.9905x; 1.7819x over previous
//
#include <hip/hip_runtime.h>
#include <math.h>

// resRNN forward: N=256, L=1024, inp=521 (=8 x + 1 storage + 512 hx), HID=512, OUT=1.
// Round 6: the falsified model was "L2-port bound". Real roof (from m134 LDS
// constants + rounds 0-5 timings): per-CU LDS instruction throughput on the
// broadcast reads of inps (~260 ds_read_b128/wave/step; 8 waves; ~12 cyc each
// ~= 25-31 K cyc/step across rounds). The inps-broadcast cost scales with
// batches-per-block; weight traffic does not. Round 0-5 ran 2 batches/block on
// 128 CUs (128 CUs idle) -> doubled the dominant term for nothing.
// Fix: 1 batch/block, 256 blocks, all 256 CUs active. Per-CU LDS instr halves,
// VALU halves, streamed phase unchanged. Residency partition kept from round 5:
// rows [0,128) AGPR (v_accvgpr asm), [128,204) LDS (152 KB), [204,520) streamed
// packed float4 (79 chunks), row 520 tail VGPR. Row->fma-chain mapping identical
// to round 5 (even->a0, odd->c0) => bit-identical per-column results.

constexpr int kN   = 256;
constexpr int kL   = 1024;
constexpr int kHin = 8;
constexpr int kHid = 512;
constexpr int kInp = kHin + 1 + kHid;        // 521
constexpr int kBlk = 512;

constexpr int RAGP  = 128;                   // W1 rows resident in AGPRs
constexpr int NAGRP = RAGP / 8;              // 16 groups of 8 rows
constexpr int RLDS  = 76;                    // W1 rows resident in LDS (152 KB)
constexpr int RRES  = RAGP + RLDS;           // 204 resident rows
constexpr int NPK   = (kInp - 1 - RRES) / 4; // 79 packed chunks of 4 streamed rows
static_assert(RLDS % 4 == 0, "LDS phase consumes 4 rows/iter");
static_assert(RRES + 4 * NPK + 1 == kInp, "row partition must cover 521 rows");

// Packed streamed weights: g_w1p[(c*512 + j)*4 + i] = W1[RRES + 4c + i][j].
__device__ __align__(16) float g_w1p[NPK * kHid * 4];

__global__ void repack_w1(const float* __restrict__ W1) {
  const int idx = blockIdx.x * 256 + threadIdx.x;
  if (idx >= NPK * kHid) return;
  const int c = idx >> 9;          // chunk
  const int j = idx & (kHid - 1);  // column
  const int r = RRES + 4 * c;
  float4 v;
  v.x = W1[(size_t)(r + 0) * kHid + j];
  v.y = W1[(size_t)(r + 1) * kHid + j];
  v.z = W1[(size_t)(r + 2) * kHid + j];
  v.w = W1[(size_t)(r + 3) * kHid + j];
  *reinterpret_cast<float4*>(&g_w1p[(size_t)idx * 4]) = v;
}

__global__
__attribute__((amdgpu_flat_work_group_size(kBlk, kBlk)))
__attribute__((amdgpu_waves_per_eu(2, 2)))
void resrnn_fwd(const float* __restrict__ x, const float* __restrict__ W1,
                const float* __restrict__ b1, const float* __restrict__ W2,
                const float* __restrict__ b2, float* __restrict__ out) {
  // inps: [0..7]=x_t, [8]=s_t, [9..520]=hx_{t-1}  (single batch)
  __shared__ __align__(16) float inps[kInp + 3];
  __shared__ float wlds[RLDS][kHid];   // W1 rows [RAGP, RRES), 152 KB
  __shared__ __align__(16) float red[8];

  const int j = threadIdx.x;           // hidden column 0..511
  const int n = blockIdx.x;            // batch element (1 per block)

  const float b2v = b2[0];
  const float w2j = W2[j];
  const float b1j = b1[j];

  float* const outp = out;                        // (N,L,1) flat
  float* const stor = out + (size_t)kN * kL;      // implied_storage

  const float* xn = x + (size_t)n * kL * kHin;

  const float* const wj  = W1 + j;                // column j, stride kHid
  const float* const wpk = g_w1p + (size_t)j * 4; // packed streamed, stride 2048 floats

  // ---- one-time W1 cache fill: rows [0,RAGP) -> AGPRs ----
  float areg[RAGP];
  #pragma unroll
  for (int r = 0; r < RAGP; ++r) {
    const float v = wj[(size_t)r * kHid];
    asm volatile("v_accvgpr_write_b32 %0, %1" : "=a"(areg[r]) : "v"(v));
  }
  // rows [RAGP, RRES) -> LDS
  for (int r = 0; r < RLDS; ++r) wlds[r][j] = wj[(size_t)(RAGP + r) * kHid];
  // tail row 520 -> one arch VGPR, loaded once
  float wtail = wj[(size_t)(kInp - 1) * kHid];
  asm volatile("" : "+v"(wtail));

  // ---- init: hx = 0, s_0 = x_0[0] ----
  inps[kHin + 1 + j] = 0.f;
  float s = xn[0];
  if (j < kHin) inps[j] = xn[j];
  if (j == 8)   inps[kHin] = s;
  if (j == 0)   stor[(size_t)n * kL] = s;
  __syncthreads();

  for (int t = 0; t < kL; ++t) {
    float a0 = b1j;   // fma chain A (even rows)
    float c0 = 0.f;   // fma chain B (odd rows)

    // ---- rows [0, RAGP): weights in AGPRs; 16 groups of 8 rows.
    // Inputs for group g+1 loaded BEFORE group g's asm block so ds_read
    // latency hides under the previous group's reads+FMAs.
    float4 nx0 = *reinterpret_cast<const float4*>(&inps[0]);
    float4 nx1 = *reinterpret_cast<const float4*>(&inps[4]);
    #pragma unroll
    for (int g = 0; g < NAGRP; ++g) {
      const float4 u0 = nx0, u1 = nx1;
      if (g + 1 < NAGRP) {
        nx0 = *reinterpret_cast<const float4*>(&inps[8 * (g + 1)]);
        nx1 = *reinterpret_cast<const float4*>(&inps[8 * (g + 1) + 4]);
      }
      float w0, w1, w2, w3, w4, w5, w6, w7;
      asm volatile(
          "v_accvgpr_read_b32 %0, %8\n\t"
          "v_accvgpr_read_b32 %1, %9\n\t"
          "v_accvgpr_read_b32 %2, %10\n\t"
          "v_accvgpr_read_b32 %3, %11\n\t"
          "v_accvgpr_read_b32 %4, %12\n\t"
          "v_accvgpr_read_b32 %5, %13\n\t"
          "v_accvgpr_read_b32 %6, %14\n\t"
          "v_accvgpr_read_b32 %7, %15"
          : "=v"(w0), "=v"(w1), "=v"(w2), "=v"(w3),
            "=v"(w4), "=v"(w5), "=v"(w6), "=v"(w7)
          : "a"(areg[8 * g + 0]), "a"(areg[8 * g + 1]),
            "a"(areg[8 * g + 2]), "a"(areg[8 * g + 3]),
            "a"(areg[8 * g + 4]), "a"(areg[8 * g + 5]),
            "a"(areg[8 * g + 6]), "a"(areg[8 * g + 7]));
      a0 = fmaf(u0.x, w0, a0); c0 = fmaf(u0.y, w1, c0);
      a0 = fmaf(u0.z, w2, a0); c0 = fmaf(u0.w, w3, c0);
      a0 = fmaf(u1.x, w4, a0); c0 = fmaf(u1.y, w5, c0);
      a0 = fmaf(u1.z, w6, a0); c0 = fmaf(u1.w, w7, c0);
    }

    // ---- rows [RAGP, RRES): weights in LDS, 4 rows per float4 of inps ----
    #pragma unroll 4
    for (int k = 0; k < RLDS; k += 4) {
      const float4 v = *reinterpret_cast<const float4*>(&inps[RAGP + k]);
      const float wa = wlds[k + 0][j];
      const float wb = wlds[k + 1][j];
      const float wc = wlds[k + 2][j];
      const float wd = wlds[k + 3][j];
      a0 = fmaf(v.x, wa, a0); c0 = fmaf(v.y, wb, c0);
      a0 = fmaf(v.z, wc, a0); c0 = fmaf(v.w, wd, c0);
    }

    // ---- rows [RRES, 520): streamed packed from L2, one dwordx4 per 4 rows ----
    #pragma unroll 8
    for (int c = 0; c < NPK; ++c) {
      const float4 wv = *reinterpret_cast<const float4*>(&wpk[(size_t)c * kHid * 4]);
      const float4 v  = *reinterpret_cast<const float4*>(&inps[RRES + 4 * c]);
      a0 = fmaf(v.x, wv.x, a0); c0 = fmaf(v.y, wv.y, c0);
      a0 = fmaf(v.z, wv.z, a0); c0 = fmaf(v.w, wv.w, c0);
    }
    a0 = fmaf(inps[kInp - 1], wtail, a0);  // tail row 520

    const float h = tanhf(a0 + c0);

    // ---- out = hx_new . W2 + b2 : wave shuffle reduce, then LDS combine ----
    float p = h * w2j;
    #pragma unroll
    for (int off = 32; off > 0; off >>= 1) p += __shfl_down(p, off, 64);
    const int lane = j & 63, wid = j >> 6;
    if (lane == 0) red[wid] = p;
    __syncthreads();  // barrier A: all inps reads done; red[] populated

    const float4 r0 = *reinterpret_cast<const float4*>(&red[0]);
    const float4 r1 = *reinterpret_cast<const float4*>(&red[4]);
    const float o = (((r0.x + r0.y) + (r0.z + r0.w)) +
                     ((r1.x + r1.y) + (r1.z + r1.w))) + b2v;  // same in all threads
    if (j == 0) outp[(size_t)n * kL + t] = o;

    // ---- stage step t+1: hx, x, s = s + x_{t+1}[0] - out_t ----
    inps[kHin + 1 + j] = h;
    if (t + 1 < kL) {
      const float* xr = xn + (size_t)(t + 1) * kHin;
      s += xr[0] - o;  // replicated identically across threads
      if (j < kHin) inps[j] = xr[j];
      if (j == 8)   inps[kHin] = s;
      if (j == 0)   stor[(size_t)n * kL + t + 1] = s;
    }
    __syncthreads();  // barrier B: next-step inp fully staged
  }
}

extern "C" void kernel_launch(void* const* d_in, const int* in_sizes, int n_in,
                              void* d_out, int out_size, void* d_ws, size_t ws_size,
                              hipStream_t stream) {
  const float* x  = (const float*)d_in[0];
  const float* W1 = (const float*)d_in[1];
  const float* b1 = (const float*)d_in[2];
  const float* W2 = (const float*)d_in[3];
  const float* b2 = (const float*)d_in[4];
  float* out = (float*)d_out;

  // one-time (per launch) repack of streamed W1 rows into float4-per-thread form
  {
    const int total = NPK * kHid;                 // 40448
    dim3 g((total + 255) / 256), b(256);
    hipLaunchKernelGGL(repack_w1, g, b, 0, stream, W1);
  }

  dim3 grid(kN);          // 256 blocks -> 1 batch element per block, all CUs
  dim3 block(kBlk);       // 512 threads = 8 waves
  hipLaunchKernelGGL(resrnn_fwd, grid, block, 0, stream, x, W1, b1, W2, b2, out);
}